// Round 3
// baseline (346.882 us; speedup 1.0000x reference)
//
#include <hip/hip_runtime.h>

#define Hd 128
#define LDA 136     // LDS leading dim (bf16 elems)
#define EPKCAP 448  // per-wave packed edge-src cache (ints)

typedef __attribute__((ext_vector_type(8))) short short8;   // 8 bf16 = 4 VGPRs
typedef __attribute__((ext_vector_type(4))) float f32x4;

__device__ __forceinline__ unsigned short f2bf(float f) {
    union { float f; unsigned u; } v; v.f = f;
    unsigned r = v.u + 0x7FFFu + ((v.u >> 16) & 1u);   // RNE
    return (unsigned short)(r >> 16);
}

// ---------- graph prep ----------
// histogram over (rel*N + dst) buckets  (rel-major: per-(wave,rel) edges contiguous)
__global__ __launch_bounds__(256) void count_kernel(const int* __restrict__ dst,
                                                    const int* __restrict__ et,
                                                    int* __restrict__ cnt2, int E, int N) {
    int e = blockIdx.x * 256 + threadIdx.x;
    if (e < E) atomicAdd(&cnt2[et[e] * N + dst[e]], 1);
}

__global__ __launch_bounds__(256) void reduce_kernel(const int* __restrict__ cnt2,
                                                     int* __restrict__ bsum, int n) {
    __shared__ int ws[4];
    const int tid = threadIdx.x;
    int i = blockIdx.x * 256 + tid;
    int v = (i < n) ? cnt2[i] : 0;
#pragma unroll
    for (int off = 32; off > 0; off >>= 1) v += __shfl_down(v, off);
    if ((tid & 63) == 0) ws[tid >> 6] = v;
    __syncthreads();
    if (tid == 0) bsum[blockIdx.x] = ws[0] + ws[1] + ws[2] + ws[3];
}

// exclusive scan of cnt2 -> cur
__global__ __launch_bounds__(256) void apply_kernel(const int* __restrict__ cnt2,
                                                    const int* __restrict__ bsum,
                                                    int* __restrict__ cur, int n) {
    __shared__ int wsum[4];
    __shared__ int bpre_s;
    const int tid = threadIdx.x;
    const int lane = tid & 63, wid = tid >> 6;
    int p = 0;
    for (int k = tid; k < blockIdx.x; k += 256) p += bsum[k];
#pragma unroll
    for (int off = 32; off > 0; off >>= 1) p += __shfl_down(p, off);
    if (lane == 0) wsum[wid] = p;
    __syncthreads();
    if (tid == 0) bpre_s = wsum[0] + wsum[1] + wsum[2] + wsum[3];
    __syncthreads();
    int i = blockIdx.x * 256 + tid;
    int x = (i < n) ? cnt2[i] : 0;
    int incl = x;
#pragma unroll
    for (int off = 1; off < 64; off <<= 1) {
        int t = __shfl_up(incl, off);
        if (lane >= off) incl += t;
    }
    __syncthreads();
    if (lane == 63) wsum[wid] = incl;
    __syncthreads();
    int wpre = 0;
    for (int k = 0; k < wid; ++k) wpre += wsum[k];
    if (i < n) cur[i] = incl - x + wpre + bpre_s;
}

// counting-sort placement: epk sorted by (rel,dst), payload = src.
// post-condition: cur[b] == end offset of bucket b (start(b) = cur[b-1], cur[-1]=0)
__global__ __launch_bounds__(256) void place_kernel(const int* __restrict__ src,
                                                    const int* __restrict__ dst,
                                                    const int* __restrict__ et,
                                                    int* __restrict__ cur,
                                                    unsigned int* __restrict__ epk, int E, int N) {
    int e = blockIdx.x * 256 + threadIdx.x;
    if (e < E) {
        int pos = atomicAdd(&cur[et[e] * N + dst[e]], 1);
        epk[pos] = (unsigned int)src[e];
    }
}

// ---------- merged dtype prep: blocks 0..17 transpose weights, rest convert x ----------
__global__ __launch_bounds__(256) void cvt_prep_kernel(const float* __restrict__ x,
                                                       unsigned short* __restrict__ xbf,
                                                       int n4,
                                                       const float* __restrict__ root1,
                                                       const float* __restrict__ W1,
                                                       const float* __restrict__ root2,
                                                       const float* __restrict__ W2,
                                                       unsigned short* __restrict__ Bt) {
    const int tid = threadIdx.x;
    if (blockIdx.x < 18) {
        __shared__ float S[32 * 129];
        const int b = blockIdx.x;
        const float* Ws;
        if (b == 0)       Ws = root1;
        else if (b < 9)   Ws = W1 + (size_t)(b - 1) * 16384;
        else if (b == 9)  Ws = root2;
        else              Ws = W2 + (size_t)(b - 10) * 16384;
        unsigned short* Bd = Bt + (size_t)b * 16384;
        for (int s = 0; s < 4; ++s) {
            __syncthreads();
#pragma unroll
            for (int i = 0; i < 16; ++i) {
                int idx = i * 256 + tid;
                int k = idx >> 7, n = idx & 127;
                S[k * 129 + n] = Ws[(size_t)(32 * s + k) * 128 + n];
            }
            __syncthreads();
#pragma unroll
            for (int i = 0; i < 16; ++i) {
                int idx = i * 256 + tid;
                int n = idx >> 5, kk = idx & 31;
                Bd[n * 128 + 32 * s + kk] = f2bf(S[kk * 129 + n]);
            }
        }
    } else {
        const int stride = (gridDim.x - 18) * 256;
        for (int i = (blockIdx.x - 18) * 256 + tid; i < n4; i += stride) {
            float4 v = ((const float4*)x)[i];
            ushort4 o;
            o.x = f2bf(v.x); o.y = f2bf(v.y); o.z = f2bf(v.z); o.w = f2bf(v.w);
            ((ushort4*)xbf)[i] = o;
        }
    }
}

// ---------- fully fused layer: hoisted CSR/epk in LDS + pipelined edge gathers ----------
// acc = A0@Bt[0] + sum_r meangather_r(A0)@Bt[1+r]   (K_eff = 1152)
// mode 1: outb = bf16(relu(acc + bias))        mode 2: outf = relu(acc+bias).Wc + bc
__global__ __launch_bounds__(256, 2) void gemm_fused(const unsigned short* __restrict__ A0,
                                                     const int* __restrict__ cur,
                                                     const unsigned int* __restrict__ epk,
                                                     const unsigned short* __restrict__ Bt9,
                                                     const float* __restrict__ bias,
                                                     const float* __restrict__ Wc,
                                                     const float* __restrict__ bc,
                                                     unsigned short* __restrict__ outb,
                                                     float* __restrict__ outf,
                                                     int M, int mode) {
    __shared__ __align__(16) unsigned short As[128 * LDA];   // 34816 B
    __shared__ __align__(16) unsigned short Bs[128 * LDA];   // 34816 B
    __shared__ int bnd[4][8][33];                             // 4224 B: bucket boundaries / wave
    __shared__ int offs[4][8];                                // 128 B: packed epkl offsets
    __shared__ unsigned epkl[4][EPKCAP];                      // 7168 B: packed edge srcs
    // total 81,152 B -> 2 blocks/CU

    const int tid = threadIdx.x;
    const int rowBase = blockIdx.x * 128;
    const int wave = tid >> 6, lane = tid & 63;
    const int lm = lane & 15, lk = (lane >> 4) * 8;
    const unsigned* x32 = (const unsigned*)A0;   // 2 bf16 per uint

    // ---- block-start hoist (per-wave state; no cross-wave sharing, no barriers) ----
    const int w0 = rowBase + wave * 32;
#pragma unroll
    for (int r = 0; r < 8; ++r) {
        if (lane < 33) {
            int j = w0 - 1 + lane; if (j > M - 1) j = M - 1;   // tail rows -> empty buckets
            int idx = r * M + j;
            bnd[wave][r][lane] = (idx < 0) ? 0 : cur[idx];
        }
    }
    {
        int off = 0;
#pragma unroll 1
        for (int r = 0; r < 8; ++r) {
            if (lane == 0) offs[wave][r] = off;
            int beg = bnd[wave][r][0];
            int lenr = bnd[wave][r][32] - beg;
            for (int i = lane; i < lenr; i += 64) {
                int o = off + i;
                if (o < EPKCAP) epkl[wave][o] = epk[(size_t)beg + i];
            }
            off += lenr;
        }
    }

    f32x4 acc[2][8];
#pragma unroll
    for (int mt = 0; mt < 2; ++mt)
#pragma unroll
        for (int nt = 0; nt < 8; ++nt) acc[mt][nt] = (f32x4){0.f, 0.f, 0.f, 0.f};

    // ---- per-stage pipeline state (set by PREP, consumed one stage later) ----
    int bvec = 0, begS = 0, len = 0, offr = 0;
    float winv = 1.f;
    unsigned ep0 = 0, ep1 = 0;
    unsigned pv[8];

// edge src for wave-uniform flat index ii within the current stage
#define SRCI(ii) ((ii) < 64 ? (unsigned)__builtin_amdgcn_readlane((int)ep0, (ii)) \
                : (ii) < 128 ? (unsigned)__builtin_amdgcn_readlane((int)ep1, (ii) - 64) \
                : (offr + (ii)) < EPKCAP ? epkl[wave][offr + (ii)] \
                : epk[(size_t)begS + (ii)])

// stage RR metadata + first 8 row-gathers issued (latency hides under following MFMA)
#define PREP(RR) do { \
    bvec = (lane < 33) ? bnd[wave][RR][lane] : 0; \
    offr = offs[wave][RR]; \
    begS = __builtin_amdgcn_readlane(bvec, 0); \
    len  = __builtin_amdgcn_readlane(bvec, 32) - begS; \
    int _c = __shfl_down(bvec, 1) - bvec; \
    winv = 1.0f / (float)((_c < 1) ? 1 : _c); \
    ep0 = 0; ep1 = 0; \
    if (lane < len)      ep0 = (offr + lane < EPKCAP) ? epkl[wave][offr + lane] : epk[(size_t)begS + lane]; \
    if (64 + lane < len) ep1 = (offr + 64 + lane < EPKCAP) ? epkl[wave][offr + 64 + lane] : epk[(size_t)begS + 64 + lane]; \
    _Pragma("unroll") \
    for (int _k = 0; _k < 8; ++_k) { \
        pv[_k] = 0; \
        if (_k < len) pv[_k] = x32[(size_t)SRCI(_k) * 64 + lane]; \
    } \
} while (0)

#define MFMA_BLOCK() do { \
    _Pragma("unroll") \
    for (int ks = 0; ks < 4; ++ks) { \
        const int k0 = ks * 32 + lk; \
        short8 af0 = *(const short8*)&As[(wave * 32 + lm) * LDA + k0]; \
        short8 af1 = *(const short8*)&As[(wave * 32 + 16 + lm) * LDA + k0]; \
        _Pragma("unroll") \
        for (int nt = 0; nt < 8; ++nt) { \
            short8 bf = *(const short8*)&Bs[(nt * 16 + lm) * LDA + k0]; \
            acc[0][nt] = __builtin_amdgcn_mfma_f32_16x16x32_bf16(af0, bf, acc[0][nt], 0, 0, 0); \
            acc[1][nt] = __builtin_amdgcn_mfma_f32_16x16x32_bf16(af1, bf, acc[1][nt], 0, 0, 0); \
        } \
    } \
} while (0)

    // ---- stage "root": direct rows of A0 ----
#pragma unroll
    for (int i = 0; i < 8; ++i) {
        int idx = i * 256 + tid;
        int r = idx >> 4, c16 = idx & 15;
        int grow = rowBase + r; if (grow >= M) grow = M - 1;
        *(float4*)&As[r * LDA + c16 * 8] = *(const float4*)&A0[(size_t)grow * Hd + c16 * 8];
        *(float4*)&Bs[r * LDA + c16 * 8] = *(const float4*)&Bt9[idx * 8];
    }
    __syncthreads();
    PREP(0);            // rel-0's first gathers fly during the root MFMA
    MFMA_BLOCK();

#pragma unroll 1
    for (int rr = 0; rr < 8; ++rr) {
        __syncthreads();   // previous MFMA's As/Bs reads complete
        {
            // Bs <- weights of rel rr (independent loads, issue first)
            const unsigned short* Btt = Bt9 + (size_t)(rr + 1) * 16384;
#pragma unroll
            for (int i = 0; i < 8; ++i) {
                int idx = i * 256 + tid;
                *(float4*)&Bs[(idx >> 4) * LDA + (idx & 15) * 8] = *(const float4*)&Btt[idx * 8];
            }
            // As <- per-node means of rel rr (walk edges; 2-group pipelined loads)
            float a0 = 0.f, a1 = 0.f;
            int m = 0;
            int bn = __builtin_amdgcn_readlane(bvec, 1) - begS;  // relative next boundary
            unsigned ua[8], ub[8];

#define FLUSH() do { \
    float _wv = __int_as_float(__builtin_amdgcn_readlane(__float_as_int(winv), m)); \
    unsigned _pk = (unsigned)f2bf(a0 * _wv) | ((unsigned)f2bf(a1 * _wv) << 16); \
    *(unsigned*)&As[(wave * 32 + m) * LDA + lane * 2] = _pk; \
    a0 = 0.f; a1 = 0.f; ++m; \
    bn = (m < 32) ? __builtin_amdgcn_readlane(bvec, m + 1) - begS : 0x7fffffff; \
} while (0)

#define ISSUEG(BUF, EB) { \
    _Pragma("unroll") \
    for (int _k = 0; _k < 8; ++_k) { \
        int _ii = (EB) + _k; \
        BUF[_k] = 0; \
        if (_ii < len) BUF[_k] = x32[(size_t)SRCI(_ii) * 64 + lane]; \
    } }

#define CONSG(BUF, EB) { \
    _Pragma("unroll") \
    for (int _k = 0; _k < 8; ++_k) { \
        int _ii = (EB) + _k; \
        if (_ii < len) { \
            while (_ii >= bn) FLUSH(); \
            a0 += __uint_as_float(BUF[_k] << 16); \
            a1 += __uint_as_float(BUF[_k] & 0xffff0000u); \
        } \
    } }

            ISSUEG(ub, 8);      // group 1 in flight while we consume group 0 (pv)
            CONSG(pv, 0);
#pragma unroll 1
            for (int e = 8; e < len; e += 16) {
                ISSUEG(ua, e + 8);
                CONSG(ub, e);
                ISSUEG(ub, e + 16);
                CONSG(ua, e + 8);
            }
            while (m < 32) FLUSH();   // drain (zero rows for empty/tail buckets)
#undef FLUSH
#undef ISSUEG
#undef CONSG
        }
        __syncthreads();
        if (rr < 7) PREP(rr + 1);    // next stage's first gathers fly during this MFMA
        MFMA_BLOCK();
    }
#undef PREP
#undef SRCI
#undef MFMA_BLOCK

    // epilogue. C/D layout: col = nt*16 + lm, row = wave*32 + mt*16 + (lane>>4)*4 + reg
    const int rquad = (lane >> 4) * 4;
    float biasr[8], wc[8];
#pragma unroll
    for (int nt = 0; nt < 8; ++nt) biasr[nt] = bias[nt * 16 + lm];
    if (mode == 2) {
#pragma unroll
        for (int nt = 0; nt < 8; ++nt) wc[nt] = Wc[nt * 16 + lm];
    }
    const float bc0 = (mode == 2) ? bc[0] : 0.f;

#pragma unroll
    for (int mt = 0; mt < 2; ++mt)
#pragma unroll
        for (int reg = 0; reg < 4; ++reg) {
            int row = rowBase + wave * 32 + mt * 16 + rquad + reg;
            if (mode == 1) {
                if (row >= M) continue;
#pragma unroll
                for (int nt = 0; nt < 8; ++nt) {
                    float v = fmaxf(acc[mt][nt][reg] + biasr[nt], 0.f);
                    outb[(size_t)row * Hd + nt * 16 + lm] = f2bf(v);
                }
            } else {
                float s = 0.f;
#pragma unroll
                for (int nt = 0; nt < 8; ++nt)
                    s += fmaxf(acc[mt][nt][reg] + biasr[nt], 0.f) * wc[nt];
                s += __shfl_xor(s, 1);
                s += __shfl_xor(s, 2);
                s += __shfl_xor(s, 4);
                s += __shfl_xor(s, 8);
                if (lm == 0 && row < M) outf[row] = s + bc0;
            }
        }
}

extern "C" void kernel_launch(void* const* d_in, const int* in_sizes, int n_in,
                              void* d_out, int out_size, void* d_ws, size_t ws_size,
                              hipStream_t stream) {
    const float* x     = (const float*)d_in[0];
    const int*   ei    = (const int*)d_in[1];
    const int*   et    = (const int*)d_in[2];
    const float* W1    = (const float*)d_in[3];
    const float* root1 = (const float*)d_in[4];
    const float* b1    = (const float*)d_in[5];
    const float* W2    = (const float*)d_in[6];
    const float* root2 = (const float*)d_in[7];
    const float* b2    = (const float*)d_in[8];
    const float* Wc    = (const float*)d_in[9];
    const float* bc    = (const float*)d_in[10];
    float* out = (float*)d_out;

    const int N = in_sizes[0] / Hd;
    const int E = in_sizes[2];
    const int* src  = ei;
    const int* dstp = ei + E;

    const size_t NH = (size_t)N * Hd;
    const int n2 = N * 8;                    // (rel,dst) bucket count
    const int nBlocks2 = (n2 + 255) / 256;

    size_t off = 0;
    auto carve = [&](size_t bytes) -> char* {
        char* p = (char*)d_ws + off;
        off += (bytes + 255) & ~(size_t)255;
        return p;
    };
    unsigned short* xbf  = (unsigned short*)carve(NH * 2);
    unsigned short* hbf  = (unsigned short*)carve(NH * 2);
    unsigned short* Bt   = (unsigned short*)carve((size_t)2 * 9 * 16384 * 2);
    int*            cnt2 = (int*)carve((size_t)n2 * 4);
    int*            cur  = (int*)carve((size_t)n2 * 4);
    int*            bsum = (int*)carve((size_t)nBlocks2 * 4);
    unsigned int*   epk  = (unsigned int*)carve((size_t)E * 4);
    if (off > ws_size) return;

    // graph prep: histogram -> CSR over (rel*N+dst)
    hipMemsetAsync(cnt2, 0, (size_t)n2 * 4, stream);
    count_kernel<<<(E + 255) / 256, 256, 0, stream>>>(dstp, et, cnt2, E, N);
    reduce_kernel<<<nBlocks2, 256, 0, stream>>>(cnt2, bsum, n2);
    apply_kernel<<<nBlocks2, 256, 0, stream>>>(cnt2, bsum, cur, n2);
    place_kernel<<<(E + 255) / 256, 256, 0, stream>>>(src, dstp, et, cur, epk, E, N);

    // dtype prep: weights transpose (blocks 0..17) + x cvt (grid-stride)
    const int n4 = (int)(NH / 4);
    cvt_prep_kernel<<<18 + 512, 256, 0, stream>>>(x, xbf, n4, root1, W1, root2, W2, Bt);

    const int Mtiles = (N + 127) / 128;

    // layer 1: fused gather+GEMM -> hbf (relu, bf16)
    gemm_fused<<<Mtiles, 256, 0, stream>>>(xbf, cur, epk, Bt, b1, nullptr, nullptr,
                                           hbf, nullptr, N, 1);
    // layer 2: fused gather+GEMM + classifier -> out
    gemm_fused<<<Mtiles, 256, 0, stream>>>(hbf, cur, epk, Bt + (size_t)9 * 16384, b2, Wc, bc,
                                           nullptr, out, N, 2);
}

// Round 4
// 306.125 us; speedup vs baseline: 1.1331x; 1.1331x over previous
//
#include <hip/hip_runtime.h>

#define Hd 128
#define LDA 136     // LDS leading dim (bf16 elems)
#define EPKCAP 448  // per-wave packed edge-src cache (ints), zero-padded

typedef __attribute__((ext_vector_type(8))) short short8;   // 8 bf16 = 4 VGPRs
typedef __attribute__((ext_vector_type(4))) float f32x4;

__device__ __forceinline__ unsigned short f2bf(float f) {
    union { float f; unsigned u; } v; v.f = f;
    unsigned r = v.u + 0x7FFFu + ((v.u >> 16) & 1u);   // RNE
    return (unsigned short)(r >> 16);
}

// ---------- graph prep ----------
// histogram over (rel*N + dst) buckets  (rel-major: per-(wave,rel) edges contiguous)
__global__ __launch_bounds__(256) void count_kernel(const int* __restrict__ dst,
                                                    const int* __restrict__ et,
                                                    int* __restrict__ cnt2, int E, int N) {
    int e = blockIdx.x * 256 + threadIdx.x;
    if (e < E) atomicAdd(&cnt2[et[e] * N + dst[e]], 1);
}

__global__ __launch_bounds__(256) void reduce_kernel(const int* __restrict__ cnt2,
                                                     int* __restrict__ bsum, int n) {
    __shared__ int ws[4];
    const int tid = threadIdx.x;
    int i = blockIdx.x * 256 + tid;
    int v = (i < n) ? cnt2[i] : 0;
#pragma unroll
    for (int off = 32; off > 0; off >>= 1) v += __shfl_down(v, off);
    if ((tid & 63) == 0) ws[tid >> 6] = v;
    __syncthreads();
    if (tid == 0) bsum[blockIdx.x] = ws[0] + ws[1] + ws[2] + ws[3];
}

// exclusive scan of cnt2 -> cur
__global__ __launch_bounds__(256) void apply_kernel(const int* __restrict__ cnt2,
                                                    const int* __restrict__ bsum,
                                                    int* __restrict__ cur, int n) {
    __shared__ int wsum[4];
    __shared__ int bpre_s;
    const int tid = threadIdx.x;
    const int lane = tid & 63, wid = tid >> 6;
    int p = 0;
    for (int k = tid; k < blockIdx.x; k += 256) p += bsum[k];
#pragma unroll
    for (int off = 32; off > 0; off >>= 1) p += __shfl_down(p, off);
    if (lane == 0) wsum[wid] = p;
    __syncthreads();
    if (tid == 0) bpre_s = wsum[0] + wsum[1] + wsum[2] + wsum[3];
    __syncthreads();
    int i = blockIdx.x * 256 + tid;
    int x = (i < n) ? cnt2[i] : 0;
    int incl = x;
#pragma unroll
    for (int off = 1; off < 64; off <<= 1) {
        int t = __shfl_up(incl, off);
        if (lane >= off) incl += t;
    }
    __syncthreads();
    if (lane == 63) wsum[wid] = incl;
    __syncthreads();
    int wpre = 0;
    for (int k = 0; k < wid; ++k) wpre += wsum[k];
    if (i < n) cur[i] = incl - x + wpre + bpre_s;
}

// counting-sort placement: epk sorted by (rel,dst), payload = src.
// post-condition: cur[b] == end offset of bucket b (start(b) = cur[b-1], cur[-1]=0)
__global__ __launch_bounds__(256) void place_kernel(const int* __restrict__ src,
                                                    const int* __restrict__ dst,
                                                    const int* __restrict__ et,
                                                    int* __restrict__ cur,
                                                    unsigned int* __restrict__ epk, int E, int N) {
    int e = blockIdx.x * 256 + threadIdx.x;
    if (e < E) {
        int pos = atomicAdd(&cur[et[e] * N + dst[e]], 1);
        epk[pos] = (unsigned int)src[e];
    }
}

// ---------- merged dtype prep: blocks 0..17 transpose weights, rest convert x ----------
__global__ __launch_bounds__(256) void cvt_prep_kernel(const float* __restrict__ x,
                                                       unsigned short* __restrict__ xbf,
                                                       int n4,
                                                       const float* __restrict__ root1,
                                                       const float* __restrict__ W1,
                                                       const float* __restrict__ root2,
                                                       const float* __restrict__ W2,
                                                       unsigned short* __restrict__ Bt) {
    const int tid = threadIdx.x;
    if (blockIdx.x < 18) {
        __shared__ float S[32 * 129];
        const int b = blockIdx.x;
        const float* Ws;
        if (b == 0)       Ws = root1;
        else if (b < 9)   Ws = W1 + (size_t)(b - 1) * 16384;
        else if (b == 9)  Ws = root2;
        else              Ws = W2 + (size_t)(b - 10) * 16384;
        unsigned short* Bd = Bt + (size_t)b * 16384;
        for (int s = 0; s < 4; ++s) {
            __syncthreads();
#pragma unroll
            for (int i = 0; i < 16; ++i) {
                int idx = i * 256 + tid;
                int k = idx >> 7, n = idx & 127;
                S[k * 129 + n] = Ws[(size_t)(32 * s + k) * 128 + n];
            }
            __syncthreads();
#pragma unroll
            for (int i = 0; i < 16; ++i) {
                int idx = i * 256 + tid;
                int n = idx >> 5, kk = idx & 31;
                Bd[n * 128 + 32 * s + kk] = f2bf(S[kk * 129 + n]);
            }
        }
    } else {
        const int stride = (gridDim.x - 18) * 256;
        for (int i = (blockIdx.x - 18) * 256 + tid; i < n4; i += stride) {
            float4 v = ((const float4*)x)[i];
            ushort4 o;
            o.x = f2bf(v.x); o.y = f2bf(v.y); o.z = f2bf(v.z); o.w = f2bf(v.w);
            ((ushort4*)xbf)[i] = o;
        }
    }
}

// ---------- fully fused layer: unconditional clamped gather loads (countable vmcnt) ----------
// acc = A0@Bt[0] + sum_r meangather_r(A0)@Bt[1+r]   (K_eff = 1152)
// mode 1: outb = bf16(relu(acc + bias))        mode 2: outf = relu(acc+bias).Wc + bc
__global__ __launch_bounds__(256, 2) void gemm_fused(const unsigned short* __restrict__ A0,
                                                     const int* __restrict__ cur,
                                                     const unsigned int* __restrict__ epk,
                                                     const unsigned short* __restrict__ Bt9,
                                                     const float* __restrict__ bias,
                                                     const float* __restrict__ Wc,
                                                     const float* __restrict__ bc,
                                                     unsigned short* __restrict__ outb,
                                                     float* __restrict__ outf,
                                                     int M, int mode) {
    __shared__ __align__(16) unsigned short As[128 * LDA];   // 34816 B
    __shared__ __align__(16) unsigned short Bs[128 * LDA];   // 34816 B
    __shared__ int bnd[4][8][33];                             // 4224 B
    __shared__ int offs[4][8];                                // 128 B
    __shared__ unsigned epkl[4][EPKCAP];                      // 7168 B (zero-padded)
    // total 81,152 B -> 2 blocks/CU

    const int tid = threadIdx.x;
    const int rowBase = blockIdx.x * 128;
    const int wave = tid >> 6, lane = tid & 63;
    const int lm = lane & 15, lk = (lane >> 4) * 8;
    const unsigned* x32 = (const unsigned*)A0;   // 2 bf16 per uint

    // ---- block-start hoist (per-wave state; no cross-wave sharing, no barriers) ----
    const int w0 = rowBase + wave * 32;
#pragma unroll
    for (int r = 0; r < 8; ++r) {
        if (lane < 33) {
            int j = w0 - 1 + lane; if (j > M - 1) j = M - 1;   // tail rows -> empty buckets
            int idx = r * M + j;
            bnd[wave][r][lane] = (idx < 0) ? 0 : cur[idx];
        }
    }
    {
        int off = 0;
#pragma unroll 1
        for (int r = 0; r < 8; ++r) {
            if (lane == 0) offs[wave][r] = off;
            int beg = bnd[wave][r][0];
            int lenr = bnd[wave][r][32] - beg;
            for (int i = lane; i < lenr; i += 64) {
                int o = off + i;
                if (o < EPKCAP) epkl[wave][o] = epk[(size_t)beg + i];
            }
            off += lenr;
        }
        for (int i = off + lane; i < EPKCAP; i += 64) epkl[wave][i] = 0;  // pad: node 0 (valid row)
    }

    f32x4 acc[2][8];
#pragma unroll
    for (int mt = 0; mt < 2; ++mt)
#pragma unroll
        for (int nt = 0; nt < 8; ++nt) acc[mt][nt] = (f32x4){0.f, 0.f, 0.f, 0.f};

    // ---- per-stage pipeline state ----
    int bvec = 0, begS = 0, len = 0, offr = 0;
    float winv = 1.f;
    unsigned pv[8], ua[8], ub[8], uc[8];

// unconditional group load: clamped LDS src lookup -> unconditional row load
#define LOADG(BUF, EB) { _Pragma("unroll") \
    for (int _k = 0; _k < 8; ++_k) { \
        int _idx = offr + (EB) + _k; \
        _idx = (_idx < EPKCAP) ? _idx : (EPKCAP - 1); \
        unsigned _s = epkl[wave][_idx]; \
        BUF[_k] = x32[(size_t)_s * 64 + lane]; \
    } }

// stage RR metadata + first 8 row-gathers issued (fly under the following MFMA)
#define PREP(RR) do { \
    bvec = bnd[wave][RR][(lane < 33) ? lane : 0]; \
    offr = __builtin_amdgcn_readfirstlane(offs[wave][RR]); \
    begS = __builtin_amdgcn_readlane(bvec, 0); \
    len  = __builtin_amdgcn_readlane(bvec, 32) - begS; \
    int _c = __shfl_down(bvec, 1) - bvec; \
    winv = 1.0f / (float)((_c < 1) ? 1 : _c); \
    LOADG(pv, 0); \
} while (0)

#define MFMA_BLOCK() do { \
    _Pragma("unroll") \
    for (int ks = 0; ks < 4; ++ks) { \
        const int k0 = ks * 32 + lk; \
        short8 af0 = *(const short8*)&As[(wave * 32 + lm) * LDA + k0]; \
        short8 af1 = *(const short8*)&As[(wave * 32 + 16 + lm) * LDA + k0]; \
        _Pragma("unroll") \
        for (int nt = 0; nt < 8; ++nt) { \
            short8 bf = *(const short8*)&Bs[(nt * 16 + lm) * LDA + k0]; \
            acc[0][nt] = __builtin_amdgcn_mfma_f32_16x16x32_bf16(af0, bf, acc[0][nt], 0, 0, 0); \
            acc[1][nt] = __builtin_amdgcn_mfma_f32_16x16x32_bf16(af1, bf, acc[1][nt], 0, 0, 0); \
        } \
    } \
} while (0)

#define FLUSH() do { \
    float _wv = __int_as_float(__builtin_amdgcn_readlane(__float_as_int(winv), m)); \
    unsigned _pk = (unsigned)f2bf(a0 * _wv) | ((unsigned)f2bf(a1 * _wv) << 16); \
    *(unsigned*)&As[(wave * 32 + m) * LDA + lane * 2] = _pk; \
    a0 = 0.f; a1 = 0.f; ++m; \
    bn = (m < 32) ? __builtin_amdgcn_readlane(bvec, m + 1) - begS : 0x7fffffff; \
} while (0)

// consume 8 edges: boundary flushes (no VMEM inside), masked add (no branch around loads)
#define CONSG(BUF, EB) { _Pragma("unroll") \
    for (int _k = 0; _k < 8; ++_k) { \
        int _ii = (EB) + _k; \
        while (_ii >= bn) FLUSH(); \
        unsigned _u = (_ii < len) ? BUF[_k] : 0u; \
        a0 += __uint_as_float(_u << 16); \
        a1 += __uint_as_float(_u & 0xffff0000u); \
    } }

    // ---- stage "root": direct rows of A0 ----
#pragma unroll
    for (int i = 0; i < 8; ++i) {
        int idx = i * 256 + tid;
        int r = idx >> 4, c16 = idx & 15;
        int grow = rowBase + r; if (grow >= M) grow = M - 1;
        *(float4*)&As[r * LDA + c16 * 8] = *(const float4*)&A0[(size_t)grow * Hd + c16 * 8];
        *(float4*)&Bs[r * LDA + c16 * 8] = *(const float4*)&Bt9[idx * 8];
    }
    __syncthreads();
    PREP(0);            // rel-0's first gathers fly during the root MFMA
    MFMA_BLOCK();

#pragma unroll 1
    for (int rr = 0; rr < 8; ++rr) {
        __syncthreads();   // previous MFMA's As/Bs reads complete
        const unsigned short* Btt = Bt9 + (size_t)(rr + 1) * 16384;
        float4 btmp[8];
#pragma unroll
        for (int i = 0; i < 8; ++i) btmp[i] = *(const float4*)&Btt[(i * 256 + tid) * 8];

        if (offr + len <= EPKCAP) {
            // ---- fast walk: all loads unconditional, 3-buffer round-robin ----
            float a0 = 0.f, a1 = 0.f;
            int m = 0;
            int bn = __builtin_amdgcn_readlane(bvec, 1) - begS;
            LOADG(ua, 8);
            LOADG(ub, 16);
            CONSG(pv, 0);                       // pv already complete (pre-barrier prefetch)
#pragma unroll
            for (int i = 0; i < 8; ++i) {       // Bs <- btmp (waits only on btmp loads)
                int idx = i * 256 + tid;
                *(float4*)&Bs[(idx >> 4) * LDA + (idx & 15) * 8] = btmp[i];
            }
#pragma unroll 1
            for (int e = 8; e < len; e += 24) {
                LOADG(uc, e + 16); CONSG(ua, e);
                LOADG(ua, e + 24); CONSG(ub, e + 8);
                LOADG(ub, e + 32); CONSG(uc, e + 16);
            }
            while (m < 32) FLUSH();             // drain (zero rows for empty/tail buckets)
        } else {
            // ---- slow path (packed cache overflow; ~never taken) ----
            float a0 = 0.f, a1 = 0.f;
            int m = 0;
            int bn = __builtin_amdgcn_readlane(bvec, 1) - begS;
#pragma unroll
            for (int i = 0; i < 8; ++i) {
                int idx = i * 256 + tid;
                *(float4*)&Bs[(idx >> 4) * LDA + (idx & 15) * 8] = btmp[i];
            }
#pragma unroll 1
            for (int ii = 0; ii < len; ++ii) {
                unsigned s = epk[(size_t)begS + ii];
                unsigned v = x32[(size_t)s * 64 + lane];
                while (ii >= bn) FLUSH();
                a0 += __uint_as_float(v << 16);
                a1 += __uint_as_float(v & 0xffff0000u);
            }
            while (m < 32) FLUSH();
        }
        __syncthreads();
        if (rr < 7) PREP(rr + 1);    // next stage's first gathers fly during this MFMA
        MFMA_BLOCK();
    }
#undef PREP
#undef LOADG
#undef CONSG
#undef FLUSH
#undef MFMA_BLOCK

    // epilogue. C/D layout: col = nt*16 + lm, row = wave*32 + mt*16 + (lane>>4)*4 + reg
    const int rquad = (lane >> 4) * 4;
    float biasr[8], wc[8];
#pragma unroll
    for (int nt = 0; nt < 8; ++nt) biasr[nt] = bias[nt * 16 + lm];
    if (mode == 2) {
#pragma unroll
        for (int nt = 0; nt < 8; ++nt) wc[nt] = Wc[nt * 16 + lm];
    }
    const float bc0 = (mode == 2) ? bc[0] : 0.f;

#pragma unroll
    for (int mt = 0; mt < 2; ++mt)
#pragma unroll
        for (int reg = 0; reg < 4; ++reg) {
            int row = rowBase + wave * 32 + mt * 16 + rquad + reg;
            if (mode == 1) {
                if (row >= M) continue;
#pragma unroll
                for (int nt = 0; nt < 8; ++nt) {
                    float v = fmaxf(acc[mt][nt][reg] + biasr[nt], 0.f);
                    outb[(size_t)row * Hd + nt * 16 + lm] = f2bf(v);
                }
            } else {
                float s = 0.f;
#pragma unroll
                for (int nt = 0; nt < 8; ++nt)
                    s += fmaxf(acc[mt][nt][reg] + biasr[nt], 0.f) * wc[nt];
                s += __shfl_xor(s, 1);
                s += __shfl_xor(s, 2);
                s += __shfl_xor(s, 4);
                s += __shfl_xor(s, 8);
                if (lm == 0 && row < M) outf[row] = s + bc0;
            }
        }
}

extern "C" void kernel_launch(void* const* d_in, const int* in_sizes, int n_in,
                              void* d_out, int out_size, void* d_ws, size_t ws_size,
                              hipStream_t stream) {
    const float* x     = (const float*)d_in[0];
    const int*   ei    = (const int*)d_in[1];
    const int*   et    = (const int*)d_in[2];
    const float* W1    = (const float*)d_in[3];
    const float* root1 = (const float*)d_in[4];
    const float* b1    = (const float*)d_in[5];
    const float* W2    = (const float*)d_in[6];
    const float* root2 = (const float*)d_in[7];
    const float* b2    = (const float*)d_in[8];
    const float* Wc    = (const float*)d_in[9];
    const float* bc    = (const float*)d_in[10];
    float* out = (float*)d_out;

    const int N = in_sizes[0] / Hd;
    const int E = in_sizes[2];
    const int* src  = ei;
    const int* dstp = ei + E;

    const size_t NH = (size_t)N * Hd;
    const int n2 = N * 8;                    // (rel,dst) bucket count
    const int nBlocks2 = (n2 + 255) / 256;

    size_t off = 0;
    auto carve = [&](size_t bytes) -> char* {
        char* p = (char*)d_ws + off;
        off += (bytes + 255) & ~(size_t)255;
        return p;
    };
    unsigned short* xbf  = (unsigned short*)carve(NH * 2);
    unsigned short* hbf  = (unsigned short*)carve(NH * 2);
    unsigned short* Bt   = (unsigned short*)carve((size_t)2 * 9 * 16384 * 2);
    int*            cnt2 = (int*)carve((size_t)n2 * 4);
    int*            cur  = (int*)carve((size_t)n2 * 4);
    int*            bsum = (int*)carve((size_t)nBlocks2 * 4);
    unsigned int*   epk  = (unsigned int*)carve((size_t)E * 4);
    if (off > ws_size) return;

    // graph prep: histogram -> CSR over (rel*N+dst)
    hipMemsetAsync(cnt2, 0, (size_t)n2 * 4, stream);
    count_kernel<<<(E + 255) / 256, 256, 0, stream>>>(dstp, et, cnt2, E, N);
    reduce_kernel<<<nBlocks2, 256, 0, stream>>>(cnt2, bsum, n2);
    apply_kernel<<<nBlocks2, 256, 0, stream>>>(cnt2, bsum, cur, n2);
    place_kernel<<<(E + 255) / 256, 256, 0, stream>>>(src, dstp, et, cur, epk, E, N);

    // dtype prep: weights transpose (blocks 0..17) + x cvt (grid-stride)
    const int n4 = (int)(NH / 4);
    cvt_prep_kernel<<<18 + 512, 256, 0, stream>>>(x, xbf, n4, root1, W1, root2, W2, Bt);

    const int Mtiles = (N + 127) / 128;

    // layer 1: fused gather+GEMM -> hbf (relu, bf16)
    gemm_fused<<<Mtiles, 256, 0, stream>>>(xbf, cur, epk, Bt, b1, nullptr, nullptr,
                                           hbf, nullptr, N, 1);
    // layer 2: fused gather+GEMM + classifier -> out
    gemm_fused<<<Mtiles, 256, 0, stream>>>(hbf, cur, epk, Bt + (size_t)9 * 16384, b2, Wc, bc,
                                           nullptr, out, N, 2);
}

// Round 5
// 297.685 us; speedup vs baseline: 1.1653x; 1.0284x over previous
//
#include <hip/hip_runtime.h>

#define Hd 128
#define LDA 136   // LDS leading dim (bf16 elems)
#define ZW 1152   // z row width (bf16): [root | 8 rels] * 128
#define ZW2 576   // z row width in uints

typedef __attribute__((ext_vector_type(8))) short short8;   // 8 bf16 = 4 VGPRs
typedef __attribute__((ext_vector_type(4))) float f32x4;

__device__ __forceinline__ unsigned short f2bf(float f) {
    union { float f; unsigned u; } v; v.f = f;
    unsigned r = v.u + 0x7FFFu + ((v.u >> 16) & 1u);   // RNE
    return (unsigned short)(r >> 16);
}

// ---------- graph prep (R0 structure: dst-major buckets dst*8+rel) ----------
__global__ __launch_bounds__(256) void count_kernel(const int* __restrict__ dst,
                                                    const int* __restrict__ et,
                                                    int* __restrict__ cnt2, int E) {
    int e = blockIdx.x * 256 + threadIdx.x;
    if (e < E) atomicAdd(&cnt2[dst[e] * 8 + et[e]], 1);
}

__global__ __launch_bounds__(256) void reduce_kernel(const int* __restrict__ cnt2,
                                                     int* __restrict__ bsum, int n) {
    __shared__ int ws[4];
    const int tid = threadIdx.x;
    int i = blockIdx.x * 256 + tid;
    int v = (i < n) ? cnt2[i] : 0;
#pragma unroll
    for (int off = 32; off > 0; off >>= 1) v += __shfl_down(v, off);
    if ((tid & 63) == 0) ws[tid >> 6] = v;
    __syncthreads();
    if (tid == 0) bsum[blockIdx.x] = ws[0] + ws[1] + ws[2] + ws[3];
}

// exclusive scan of cnt2 -> cur; inv2 = 1/max(cnt,1)
__global__ __launch_bounds__(256) void apply_kernel(const int* __restrict__ cnt2,
                                                    const int* __restrict__ bsum,
                                                    int* __restrict__ cur,
                                                    float* __restrict__ inv2, int n) {
    __shared__ int wsum[4];
    __shared__ int bpre_s;
    const int tid = threadIdx.x;
    const int lane = tid & 63, wid = tid >> 6;
    int p = 0;
    for (int k = tid; k < blockIdx.x; k += 256) p += bsum[k];
#pragma unroll
    for (int off = 32; off > 0; off >>= 1) p += __shfl_down(p, off);
    if (lane == 0) wsum[wid] = p;
    __syncthreads();
    if (tid == 0) bpre_s = wsum[0] + wsum[1] + wsum[2] + wsum[3];
    __syncthreads();
    int i = blockIdx.x * 256 + tid;
    int x = (i < n) ? cnt2[i] : 0;
    int incl = x;
#pragma unroll
    for (int off = 1; off < 64; off <<= 1) {
        int t = __shfl_up(incl, off);
        if (lane >= off) incl += t;
    }
    __syncthreads();
    if (lane == 63) wsum[wid] = incl;
    __syncthreads();
    int wpre = 0;
    for (int k = 0; k < wid; ++k) wpre += wsum[k];
    if (i < n) {
        cur[i] = incl - x + wpre + bpre_s;
        inv2[i] = 1.0f / (float)max(x, 1);
    }
}

// counting-sort placement: epk sorted by (dst,rel), payload = src.
// post-condition: cur[b] == end offset of bucket b (start(b) = cur[b-1], cur[-1]=0)
__global__ __launch_bounds__(256) void place_kernel(const int* __restrict__ src,
                                                    const int* __restrict__ dst,
                                                    const int* __restrict__ et,
                                                    int* __restrict__ cur,
                                                    unsigned int* __restrict__ epk, int E) {
    int e = blockIdx.x * 256 + threadIdx.x;
    if (e < E) {
        int pos = atomicAdd(&cur[dst[e] * 8 + et[e]], 1);
        epk[pos] = (unsigned int)src[e];
    }
}

// ---------- merged dtype prep: blocks 0..17 transpose weights, rest convert x ----------
__global__ __launch_bounds__(256) void cvt_prep_kernel(const float* __restrict__ x,
                                                       unsigned short* __restrict__ xbf,
                                                       int n4,
                                                       const float* __restrict__ root1,
                                                       const float* __restrict__ W1,
                                                       const float* __restrict__ root2,
                                                       const float* __restrict__ W2,
                                                       unsigned short* __restrict__ Bt) {
    const int tid = threadIdx.x;
    if (blockIdx.x < 18) {
        // Bt[b][n*128+k] = bf16(W[k*128+n]), slab-transposed (16.5 KB LDS)
        __shared__ float S[32 * 129];
        const int b = blockIdx.x;
        const float* Ws;
        if (b == 0)       Ws = root1;
        else if (b < 9)   Ws = W1 + (size_t)(b - 1) * 16384;
        else if (b == 9)  Ws = root2;
        else              Ws = W2 + (size_t)(b - 10) * 16384;
        unsigned short* Bd = Bt + (size_t)b * 16384;
        for (int s = 0; s < 4; ++s) {
            __syncthreads();
#pragma unroll
            for (int i = 0; i < 16; ++i) {     // load rows k in [32s,32s+32)
                int idx = i * 256 + tid;
                int k = idx >> 7, n = idx & 127;
                S[k * 129 + n] = Ws[(size_t)(32 * s + k) * 128 + n];
            }
            __syncthreads();
#pragma unroll
            for (int i = 0; i < 16; ++i) {     // write Bd[n][32s+kk]
                int idx = i * 256 + tid;
                int n = idx >> 5, kk = idx & 31;
                Bd[n * 128 + 32 * s + kk] = f2bf(S[kk * 129 + n]);
            }
        }
    } else {
        // grid-stride fp32 -> bf16 of x
        const int stride = (gridDim.x - 18) * 256;
        for (int i = (blockIdx.x - 18) * 256 + tid; i < n4; i += stride) {
            float4 v = ((const float4*)x)[i];
            ushort4 o;
            o.x = f2bf(v.x); o.y = f2bf(v.y); o.z = f2bf(v.z); o.w = f2bf(v.w);
            ((ushort4*)xbf)[i] = o;
        }
    }
}

// ---------- dense GEMM: z[:, ct*128:(ct+1)*128] = A @ Bt[ct]   (K = 128) ----------
// A: M x 128 bf16 row-major.  Bt[ct]: [n*128+k] transposed weights.  z: M x 1152 bf16.
__global__ __launch_bounds__(256, 2) void gemm_z(const unsigned short* __restrict__ A,
                                                 const unsigned short* __restrict__ Bt9,
                                                 unsigned short* __restrict__ z, int M) {
    __shared__ __align__(16) unsigned short As[128 * LDA];
    __shared__ __align__(16) unsigned short Bs[128 * LDA];
    const int tid = threadIdx.x;
    const int mtile = blockIdx.x / 9, ctile = blockIdx.x % 9;
    const int rowBase = mtile * 128;
    const int wave = tid >> 6, lane = tid & 63;
    const int lm = lane & 15, lk = (lane >> 4) * 8;
    const unsigned short* Btt = Bt9 + (size_t)ctile * 16384;

    // stage A-tile + B-tile
#pragma unroll
    for (int i = 0; i < 8; ++i) {
        int idx = i * 256 + tid;
        int r = idx >> 4, c16 = idx & 15;
        int grow = rowBase + r; if (grow >= M) grow = M - 1;
        *(float4*)&As[r * LDA + c16 * 8] = *(const float4*)&A[(size_t)grow * Hd + c16 * 8];
        *(float4*)&Bs[r * LDA + c16 * 8] = *(const float4*)&Btt[idx * 8];
    }

    f32x4 acc[2][8];
#pragma unroll
    for (int mt = 0; mt < 2; ++mt)
#pragma unroll
        for (int nt = 0; nt < 8; ++nt) acc[mt][nt] = (f32x4){0.f, 0.f, 0.f, 0.f};

    __syncthreads();
#pragma unroll
    for (int ks = 0; ks < 4; ++ks) {
        const int k0 = ks * 32 + lk;
        short8 af0 = *(const short8*)&As[(wave * 32 + lm) * LDA + k0];
        short8 af1 = *(const short8*)&As[(wave * 32 + 16 + lm) * LDA + k0];
#pragma unroll
        for (int nt = 0; nt < 8; ++nt) {
            short8 bf = *(const short8*)&Bs[(nt * 16 + lm) * LDA + k0];
            acc[0][nt] = __builtin_amdgcn_mfma_f32_16x16x32_bf16(af0, bf, acc[0][nt], 0, 0, 0);
            acc[1][nt] = __builtin_amdgcn_mfma_f32_16x16x32_bf16(af1, bf, acc[1][nt], 0, 0, 0);
        }
    }

    // epilogue: raw bf16 store into z (bias/relu applied later in gather_out)
    // C/D layout: col = nt*16 + lm, row = wave*32 + mt*16 + (lane>>4)*4 + reg
    const int rquad = (lane >> 4) * 4;
#pragma unroll
    for (int mt = 0; mt < 2; ++mt)
#pragma unroll
        for (int reg = 0; reg < 4; ++reg) {
            int row = rowBase + wave * 32 + mt * 16 + rquad + reg;
            if (row >= M) continue;
#pragma unroll
            for (int nt = 0; nt < 8; ++nt)
                z[(size_t)row * ZW + ctile * 128 + nt * 16 + lm] = f2bf(acc[mt][nt][reg]);
        }
}

// ---------- aggregation over (dst,rel)-sorted CSR, reading transformed z ----------
// out[i] = relu( z[i, 0:128] + bias + sum_r inv(i,r) * sum_{e in bucket(i,r)} z[src(e), (1+r)*128 : (2+r)*128] )
// mode 1: outb = bf16 rows (h)      mode 2: outf[i] = relu_row . Wc + bc
__global__ __launch_bounds__(256) void gather_out(const unsigned short* __restrict__ z,
                                                  const int* __restrict__ cur,
                                                  const unsigned int* __restrict__ epk,
                                                  const float* __restrict__ inv2,
                                                  const float* __restrict__ bias,
                                                  const float* __restrict__ Wc,
                                                  const float* __restrict__ bc,
                                                  unsigned short* __restrict__ outb,
                                                  float* __restrict__ outf,
                                                  int N, int mode) {
    const int lane = threadIdx.x & 63;
    const int node = (int)((blockIdx.x * 256 + threadIdx.x) >> 6);
    if (node >= N) return;
    int b9 = 0;
    if (lane < 9) {
        int idx = node * 8 + lane - 1;
        b9 = (idx < 0) ? 0 : cur[idx];
    }
    float winv = (lane < 8) ? inv2[node * 8 + lane] : 0.f;
    const int beg0 = __builtin_amdgcn_readfirstlane(__shfl(b9, 0));
    const int end7 = __builtin_amdgcn_readfirstlane(__shfl(b9, 8));

    // lane-parallel prefetch of up to 64 edge srcs (node total avg ~10)
    unsigned int ep_v = 0;
    if (beg0 + lane < end7) ep_v = epk[beg0 + lane];

    const unsigned int* z32 = (const unsigned int*)z;   // 2 bf16 per uint
    float t0 = 0.f, t1 = 0.f;

#pragma unroll
    for (int r = 0; r < 8; ++r) {
        const int beg = __builtin_amdgcn_readfirstlane(__shfl(b9, r));
        const int end = __builtin_amdgcn_readfirstlane(__shfl(b9, r + 1));
        const size_t colOff = (size_t)(r + 1) * 64 + lane;
        float a0 = 0.f, a1 = 0.f;
        int e = beg;
        for (; e + 1 < end; e += 2) {     // 2 outstanding loads
            int i0 = e - beg0, i1 = i0 + 1;
            unsigned int s0 = (i0 < 64)
                ? (unsigned int)__builtin_amdgcn_readfirstlane(__shfl((int)ep_v, i0))
                : epk[e];
            unsigned int s1 = (i1 < 64)
                ? (unsigned int)__builtin_amdgcn_readfirstlane(__shfl((int)ep_v, i1))
                : epk[e + 1];
            unsigned int v0 = z32[(size_t)s0 * ZW2 + colOff];
            unsigned int v1 = z32[(size_t)s1 * ZW2 + colOff];
            a0 += __uint_as_float(v0 << 16);
            a1 += __uint_as_float(v0 & 0xffff0000u);
            a0 += __uint_as_float(v1 << 16);
            a1 += __uint_as_float(v1 & 0xffff0000u);
        }
        if (e < end) {
            int i0 = e - beg0;
            unsigned int s0 = (i0 < 64)
                ? (unsigned int)__builtin_amdgcn_readfirstlane(__shfl((int)ep_v, i0))
                : epk[e];
            unsigned int v0 = z32[(size_t)s0 * ZW2 + colOff];
            a0 += __uint_as_float(v0 << 16);
            a1 += __uint_as_float(v0 & 0xffff0000u);
        }
        float w = __shfl(winv, r);
        t0 += a0 * w;
        t1 += a1 * w;
    }

    // root block (own row, coalesced) + bias + relu
    unsigned int vr = z32[(size_t)node * ZW2 + lane];
    t0 += __uint_as_float(vr << 16) + bias[2 * lane];
    t1 += __uint_as_float(vr & 0xffff0000u) + bias[2 * lane + 1];
    t0 = fmaxf(t0, 0.f);
    t1 = fmaxf(t1, 0.f);

    if (mode == 1) {
        unsigned lo = f2bf(t0), hi = f2bf(t1);
        ((unsigned int*)outb)[(size_t)node * 64 + lane] = lo | (hi << 16);
    } else {
        float s = t0 * Wc[2 * lane] + t1 * Wc[2 * lane + 1];
        s += __shfl_xor(s, 1);
        s += __shfl_xor(s, 2);
        s += __shfl_xor(s, 4);
        s += __shfl_xor(s, 8);
        s += __shfl_xor(s, 16);
        s += __shfl_xor(s, 32);
        if (lane == 0) outf[node] = s + bc[0];
    }
}

extern "C" void kernel_launch(void* const* d_in, const int* in_sizes, int n_in,
                              void* d_out, int out_size, void* d_ws, size_t ws_size,
                              hipStream_t stream) {
    const float* x     = (const float*)d_in[0];
    const int*   ei    = (const int*)d_in[1];
    const int*   et    = (const int*)d_in[2];
    const float* W1    = (const float*)d_in[3];
    const float* root1 = (const float*)d_in[4];
    const float* b1    = (const float*)d_in[5];
    const float* W2    = (const float*)d_in[6];
    const float* root2 = (const float*)d_in[7];
    const float* b2    = (const float*)d_in[8];
    const float* Wc    = (const float*)d_in[9];
    const float* bc    = (const float*)d_in[10];
    float* out = (float*)d_out;

    const int N = in_sizes[0] / Hd;
    const int E = in_sizes[2];
    const int* src  = ei;
    const int* dstp = ei + E;

    const size_t NH = (size_t)N * Hd;
    const int n2 = N * 8;                    // (dst,rel) bucket count
    const int nBlocks2 = (n2 + 255) / 256;

    size_t off = 0;
    auto carve = [&](size_t bytes) -> char* {
        char* p = (char*)d_ws + off;
        off += (bytes + 255) & ~(size_t)255;
        return p;
    };
    unsigned short* xbf  = (unsigned short*)carve(NH * 2);
    unsigned short* hbf  = (unsigned short*)carve(NH * 2);
    unsigned short* z    = (unsigned short*)carve((size_t)N * ZW * 2);
    unsigned short* Bt   = (unsigned short*)carve((size_t)2 * 9 * 16384 * 2);
    int*            cnt2 = (int*)carve((size_t)n2 * 4);
    float*          inv2 = (float*)carve((size_t)n2 * 4);
    int*            cur  = (int*)carve((size_t)n2 * 4);
    int*            bsum = (int*)carve((size_t)nBlocks2 * 4);
    unsigned int*   epk  = (unsigned int*)carve((size_t)E * 4);
    if (off > ws_size) return;

    // graph prep: histogram -> inv + CSR over (dst*8+rel)
    hipMemsetAsync(cnt2, 0, (size_t)n2 * 4, stream);
    count_kernel<<<(E + 255) / 256, 256, 0, stream>>>(dstp, et, cnt2, E);
    reduce_kernel<<<nBlocks2, 256, 0, stream>>>(cnt2, bsum, n2);
    apply_kernel<<<nBlocks2, 256, 0, stream>>>(cnt2, bsum, cur, inv2, n2);
    place_kernel<<<(E + 255) / 256, 256, 0, stream>>>(src, dstp, et, cur, epk, E);

    // dtype prep: weights transpose (blocks 0..17) + x cvt (grid-stride)
    const int n4 = (int)(NH / 4);
    cvt_prep_kernel<<<18 + 512, 256, 0, stream>>>(x, xbf, n4, root1, W1, root2, W2, Bt);

    const int Mtiles = (N + 127) / 128;
    const int nodeBlocks = (N + 3) / 4;

    // layer 1: z = x @ [root1|W1...], then aggregate -> h (relu, bf16)
    gemm_z<<<Mtiles * 9, 256, 0, stream>>>(xbf, Bt, z, N);
    gather_out<<<nodeBlocks, 256, 0, stream>>>(z, cur, epk, inv2, b1, nullptr, nullptr,
                                               hbf, nullptr, N, 1);
    // layer 2: z = h @ [root2|W2...], then aggregate + classifier -> out
    gemm_z<<<Mtiles * 9, 256, 0, stream>>>(hbf, Bt + (size_t)9 * 16384, z, N);
    gather_out<<<nodeBlocks, 256, 0, stream>>>(z, cur, epk, inv2, b2, Wc, bc,
                                               nullptr, out, N, 2);
}